// Round 1
// 171.584 us; speedup vs baseline: 1.0137x; 1.0137x over previous
//
#include <hip/hip_runtime.h>
#include <hip/hip_bf16.h>
#include <math.h>

constexpr int BB = 2;
constexpr int TT = 2048;
constexpr int EE = 1024;
constexpr int HH = 16;
constexpr int DD = 64;

typedef __bf16 v8bf __attribute__((ext_vector_type(8)));
typedef __bf16 v4bf __attribute__((ext_vector_type(4)));
typedef short  v4s  __attribute__((ext_vector_type(4)));
typedef float  v4f  __attribute__((ext_vector_type(4)));

#define MFMA16(a, b, c) __builtin_amdgcn_mfma_f32_16x16x32_bf16(a, b, c, 0, 0, 0)
#define MFMA16K16(a, b, c) __builtin_amdgcn_mfma_f32_16x16x16bf16_1k(a, b, c, 0, 0, 0)

// async global -> LDS, 16 B per lane; LDS dest = wave-uniform base + lane*16
__device__ __forceinline__ void gll16(const void* g, void* l) {
    __builtin_amdgcn_global_load_lds(
        (const __attribute__((address_space(1))) unsigned int*)g,
        (__attribute__((address_space(3))) unsigned int*)(unsigned)(uintptr_t)l,
        16, 0, 0);
}

// ---------------------------------------------------------------------------
// cast_all: x -> x_hi (bf16), wv_w -> bf16, out_w -> bf16.  8 elems/thread.
// ---------------------------------------------------------------------------
__global__ __launch_bounds__(256) void cast_all(
    const float* __restrict__ x, const float* __restrict__ wv,
    const float* __restrict__ ow,
    __bf16* __restrict__ xhi, __bf16* __restrict__ wvb, __bf16* __restrict__ owb)
{
    const int bid = blockIdx.x;
    const float* src;
    __bf16* dst;
    int base;
    if (bid < 2048)      { src = x;  dst = xhi; base = bid; }
    else if (bid < 2560) { src = wv; dst = wvb; base = bid - 2048; }
    else                 { src = ow; dst = owb; base = bid - 2560; }
    const size_t i = (size_t)base * 256 + threadIdx.x;
    float4 f0 = ((const float4*)src)[i * 2];
    float4 f1 = ((const float4*)src)[i * 2 + 1];
    float f[8] = {f0.x, f0.y, f0.z, f0.w, f1.x, f1.y, f1.z, f1.w};
    v8bf h;
    #pragma unroll
    for (int j = 0; j < 8; ++j) h[j] = (__bf16)f[j];
    *(v8bf*)(dst + i * 8) = h;
}

// ---------------------------------------------------------------------------
// bf16 MFMA GEMM: 64x128 tile, BK=32, 512 thr, 512 blocks -> 2 blocks/CU
// (4 waves/SIMD; the second resident block overlaps barrier drains).
// gll16 staging, XOR chunk swizzle, depth-1 double buffer, 1 barrier/K-iter.
// XCD-banded mapping: XCD x owns m-tiles [8x, 8x+8) -> 1MB A panel in its L2.
// MODE 0: C fp32 row-major; MODE 1: C bf16 as vxT (B,H,D,T)
// ---------------------------------------------------------------------------
template <int MODE>
__global__ __launch_bounds__(512) void gemm_bf16(
    const __bf16* __restrict__ A, const __bf16* __restrict__ Bw,
    const float* __restrict__ bias, void* __restrict__ Cout,
    int M, int N, int K)
{
    __shared__ __bf16 Ah[2][64][32];
    __shared__ __bf16 Bh[2][128][32];

    const int tid = threadIdx.x;
    const int w = tid >> 6, lane = tid & 63, quad = lane >> 4, l15 = lane & 15;
    const int bid = blockIdx.x;
    // 512 blocks = 64 m-tiles (64 rows) x 8 n-tiles (128 cols)
    const int xcd = bid & 7, slot = bid >> 3;       // slot 0..63
    const int bx = slot & 7;                        // n-tile 0..7 (fastest)
    const int by = (xcd << 3) | (slot >> 3);        // m-tile 0..63
    const int m0 = by * 64, n0 = bx * 128;
    const int wm = (w >> 2) * 32, wn = (w & 3) * 32;

    v4f acc[2][2] = {};
    float bn[2];
    #pragma unroll
    for (int ns = 0; ns < 2; ++ns) bn[ns] = bias[n0 + wn + ns * 16 + l15];

    const int srow = 16 * w + (lane >> 2);          // 0..127 (B); A uses w<4
    const int clog = (lane & 3) ^ ((srow >> 1) & 3);
    const __bf16* ag = A + (size_t)(m0 + srow) * K + clog * 8;
    const __bf16* bg = Bw + (size_t)(n0 + srow) * K + clog * 8;

    if (w < 4) gll16(ag, &Ah[0][16 * w][0]);
    gll16(bg, &Bh[0][16 * w][0]);
    __syncthreads();

    const int NIT = K / 32;
    for (int i = 0; i < NIT; ++i) {
        const int p = i & 1;
        if (i + 1 < NIT) {
            const size_t ko = (size_t)(i + 1) * 32;
            if (w < 4) gll16(ag + ko, &Ah[1 - p][16 * w][0]);
            gll16(bg + ko, &Bh[1 - p][16 * w][0]);
        }
        v8bf af[2], bf2[2];
        #pragma unroll
        for (int ms = 0; ms < 2; ++ms) {
            const int r = wm + ms * 16 + l15;
            af[ms] = *(const v8bf*)&Ah[p][r][(quad ^ ((r >> 1) & 3)) * 8];
        }
        #pragma unroll
        for (int ns = 0; ns < 2; ++ns) {
            const int r = wn + ns * 16 + l15;
            bf2[ns] = *(const v8bf*)&Bh[p][r][(quad ^ ((r >> 1) & 3)) * 8];
        }
        #pragma unroll
        for (int ms = 0; ms < 2; ++ms)
            #pragma unroll
            for (int ns = 0; ns < 2; ++ns)
                acc[ms][ns] = MFMA16(af[ms], bf2[ns], acc[ms][ns]);
        __syncthreads();
    }

    #pragma unroll
    for (int ms = 0; ms < 2; ++ms) {
        const int mbase = m0 + wm + ms * 16 + quad * 4;
        #pragma unroll
        for (int ns = 0; ns < 2; ++ns) {
            const int n = n0 + wn + ns * 16 + l15;
            if (MODE == 0) {
                float* C = (float*)Cout;
                #pragma unroll
                for (int r = 0; r < 4; ++r)
                    C[(size_t)(mbase + r) * N + n] = acc[ms][ns][r] + bn[ns];
            } else {
                const int bq = mbase >> 11, t = mbase & 2047;
                const int hh = n >> 6, dd = n & 63;
                v4bf pk;
                #pragma unroll
                for (int r = 0; r < 4; ++r) pk[r] = (__bf16)(acc[ms][ns][r] + bn[ns]);
                *(v4bf*)((__bf16*)Cout + (((size_t)bq * HH + hh) * DD + dd) * TT + t) = pk;
            }
        }
    }
}

// ---------------------------------------------------------------------------
// MFMA flash attention, software-pipelined: PV of tile j-1 issues before
// S of tile j (pa fragments held in registers across one barrier), so each
// wave always has a dependency-free MFMA cluster to hide the exp2/softmax
// VALU chain.  K double-buffered, V quad-buffered (V lifetime = 2 steps);
// all buffers overlay the dead phase-0 X/W regions -> LDS stays 55,296 B,
// 2 blocks/CU, ONE barrier per s-tile.  s_setprio around MFMA clusters.
// ---------------------------------------------------------------------------
__global__ __launch_bounds__(256, 2) void attn_mfma(
    const float* __restrict__ x,      // (B,T,E) fp32 (phase-0 Q input)
    const __bf16* __restrict__ xh,    // (B,T,E) bf16 (K)
    const float* __restrict__ watt,   // (H,D,D) fp32
    const __bf16* __restrict__ vxT,   // (B,H,D,T) bf16
    __bf16* __restrict__ o)           // (B,T,E) bf16
{
    constexpr int LDP = 72;
    __shared__ __bf16 SM[384][LDP];   // 55,296 B, overlaid:
    // phase 0:  XH rows 0..127, XL rows 128..255, Wh 256..319, Wl 320..383
    // main:     Kb0 0..63, Kb1 64..127, Vb0 128..191, Vb1 192..255,
    //           Vb2 256..319, Vb3 320..383
    __bf16 (*XH)[LDP]  = SM;
    __bf16 (*XL)[LDP]  = SM + 128;
    __bf16 (*Wh)[LDP]  = SM + 256;
    __bf16 (*Wl)[LDP]  = SM + 320;
    __bf16 (*Kb0)[LDP] = SM;
    __bf16 (*Kb1)[LDP] = SM + 64;
    __bf16 (*Vb0)[LDP] = SM + 128;
    __bf16 (*Vb1)[LDP] = SM + 192;
    __bf16 (*Vb2)[LDP] = SM + 256;
    __bf16 (*Vb3)[LDP] = SM + 320;

    const int tid = threadIdx.x;
    const int w = tid >> 6, lane = tid & 63, quad = lane >> 4, l15 = lane & 15;
    const int qt = blockIdx.x, h = blockIdx.y, b = blockIdx.z;
    const int t0 = qt * 128;

    // scale: 1/sqrt(D) * log2(e)  (scores computed in log2 domain -> exp2)
    const float WSC = 0.125f * 1.4426950408889634f;

    // ---- phase 0: stage X q-tile (fp32 -> hi/lo) and W_h^T (scaled, hi/lo)
    {
        const int row = tid >> 1, half = (tid & 1) * 32;
        const float* xp = x + ((size_t)(b * TT + t0 + row)) * EE + h * DD + half;
        #pragma unroll
        for (int c = 0; c < 4; ++c) {
            float4 f0 = ((const float4*)xp)[c * 2];
            float4 f1 = ((const float4*)xp)[c * 2 + 1];
            float f[8] = {f0.x, f0.y, f0.z, f0.w, f1.x, f1.y, f1.z, f1.w};
            v8bf hi, lo;
            #pragma unroll
            for (int j = 0; j < 8; ++j) {
                __bf16 hv = (__bf16)f[j];
                hi[j] = hv;
                lo[j] = (__bf16)(f[j] - (float)hv);
            }
            *(v8bf*)&XH[row][half + c * 8] = hi;
            *(v8bf*)&XL[row][half + c * 8] = lo;
        }
        const int r = tid >> 2, c0 = (tid & 3) * 16;
        const float* wp = watt + ((size_t)h * DD + r) * DD + c0;
        #pragma unroll
        for (int i = 0; i < 16; ++i) {
            const float f = wp[i] * WSC;
            __bf16 hv = (__bf16)f;
            Wh[c0 + i][r] = hv;                      // Wt_hi[e_out][d]
            Wl[c0 + i][r] = (__bf16)(f - (float)hv); // Wt_lo
        }
    }
    __syncthreads();

    // ---- Q = X_hi Wt_hi + X_hi Wt_lo + X_lo Wt_hi  (wave rows 32w..32w+32)
    v4f qacc[2][4] = {};
    #pragma unroll
    for (int kk = 0; kk < 2; ++kk) {
        v8bf xhf[2], xlf[2];
        #pragma unroll
        for (int mr = 0; mr < 2; ++mr) {
            xhf[mr] = *(const v8bf*)&XH[w * 32 + mr * 16 + l15][kk * 32 + quad * 8];
            xlf[mr] = *(const v8bf*)&XL[w * 32 + mr * 16 + l15][kk * 32 + quad * 8];
        }
        #pragma unroll
        for (int ns = 0; ns < 4; ++ns) {
            v8bf wh = *(const v8bf*)&Wh[ns * 16 + l15][kk * 32 + quad * 8];
            v8bf wl = *(const v8bf*)&Wl[ns * 16 + l15][kk * 32 + quad * 8];
            #pragma unroll
            for (int mr = 0; mr < 2; ++mr) {
                qacc[mr][ns] = MFMA16(xlf[mr], wh, qacc[mr][ns]);
                qacc[mr][ns] = MFMA16(xhf[mr], wl, qacc[mr][ns]);
                qacc[mr][ns] = MFMA16(xhf[mr], wh, qacc[mr][ns]);
            }
        }
    }
    __syncthreads();  // all waves done reading X/W regions

    // write Q hi/lo (C-layout scatter, wave-local rows), reload as frags
    #pragma unroll
    for (int mr = 0; mr < 2; ++mr)
        #pragma unroll
        for (int ns = 0; ns < 4; ++ns)
            #pragma unroll
            for (int r = 0; r < 4; ++r) {
                const float f = qacc[mr][ns][r];
                __bf16 hv = (__bf16)f;
                XH[w * 32 + mr * 16 + quad * 4 + r][ns * 16 + l15] = hv;
                XL[w * 32 + mr * 16 + quad * 4 + r][ns * 16 + l15] = (__bf16)(f - (float)hv);
            }
    v8bf qh[2][2], ql[2][2];
    #pragma unroll
    for (int mr = 0; mr < 2; ++mr)
        #pragma unroll
        for (int kk = 0; kk < 2; ++kk) {
            qh[mr][kk] = *(const v8bf*)&XH[w * 32 + mr * 16 + l15][kk * 32 + quad * 8];
            ql[mr][kk] = *(const v8bf*)&XL[w * 32 + mr * 16 + l15][kk * 32 + quad * 8];
        }
    __syncthreads();  // Q reloads done before staging overwrites SM

    v4f oacc[2][4] = {};
    v4f lacc[2] = {};
    v4s ones;
    #pragma unroll
    for (int j = 0; j < 4; ++j) ones[j] = (short)0x3F80;  // bf16 1.0

    const __bf16* kb = xh + (size_t)b * TT * EE + h * DD;
    const __bf16* vb = vxT + ((size_t)(b * HH + h)) * DD * TT;
    const int kr = tid >> 2, kc = (tid & 3) * 16;

    uint4 ak0, ak1, av0, av1, bk0, bk1, bv0, bv1;
    v4s paA[2][4], paB[2][4];

    auto loadR = [&](int idx, uint4& k0, uint4& k1, uint4& v0, uint4& v1) {
        const int s0 = idx * 64;
        k0 = *(const uint4*)(kb + (size_t)(s0 + kr) * EE + kc);
        k1 = *(const uint4*)(kb + (size_t)(s0 + kr) * EE + kc + 8);
        v0 = *(const uint4*)(vb + (size_t)kr * TT + s0 + kc);
        v1 = *(const uint4*)(vb + (size_t)kr * TT + s0 + kc + 8);
    };
    auto writeL = [&](__bf16 (*kbuf)[LDP], __bf16 (*vbuf)[LDP],
                      const uint4& k0, const uint4& k1,
                      const uint4& v0, const uint4& v1) {
        *(uint4*)&kbuf[kr][kc] = k0;
        *(uint4*)&kbuf[kr][kc + 8] = k1;
        *(uint4*)&vbuf[kr][kc] = v0;
        *(uint4*)&vbuf[kr][kc + 8] = v1;
    };
    // S^T = K (Q_hi + Q_lo)^T -> exp2 -> pa fragments (registers)
    auto computeS = [&](__bf16 (*kbuf)[LDP], v4s (*pa)[4]) {
        v4f sacc[2][4] = {};
        __builtin_amdgcn_s_setprio(1);
        #pragma unroll
        for (int kk = 0; kk < 2; ++kk)
            #pragma unroll
            for (int ss = 0; ss < 4; ++ss) {
                v8bf kf = *(const v8bf*)&kbuf[ss * 16 + l15][kk * 32 + quad * 8];
                #pragma unroll
                for (int mr = 0; mr < 2; ++mr) {
                    sacc[mr][ss] = MFMA16(kf, ql[mr][kk], sacc[mr][ss]);
                    sacc[mr][ss] = MFMA16(kf, qh[mr][kk], sacc[mr][ss]);
                }
            }
        __builtin_amdgcn_s_setprio(0);
        #pragma unroll
        for (int mr = 0; mr < 2; ++mr)
            #pragma unroll
            for (int ss = 0; ss < 4; ++ss) {
                v4bf pb;
                #pragma unroll
                for (int r = 0; r < 4; ++r)
                    pb[r] = (__bf16)__builtin_amdgcn_exp2f(sacc[mr][ss][r]);
                union { v4bf b; v4s s; } u;
                u.b = pb;
                pa[mr][ss] = u.s;
            }
    };
    // l += P 1 ; O += P V   (pa of the PREVIOUS tile -> zero-dep MFMAs)
    auto computePV = [&](__bf16 (*vbuf)[LDP], v4s (*pa)[4]) {
        __builtin_amdgcn_s_setprio(1);
        #pragma unroll
        for (int mr = 0; mr < 2; ++mr)
            #pragma unroll
            for (int ss = 0; ss < 4; ++ss)
                lacc[mr] = MFMA16K16(pa[mr][ss], ones, lacc[mr]);
        #pragma unroll
        for (int ss = 0; ss < 4; ++ss)
            #pragma unroll
            for (int ds = 0; ds < 4; ++ds) {
                v4s vf = *(const v4s*)&vbuf[ds * 16 + l15][ss * 16 + quad * 4];
                #pragma unroll
                for (int mr = 0; mr < 2; ++mr)
                    oacc[mr][ds] = MFMA16K16(pa[mr][ss], vf, oacc[mr][ds]);
            }
        __builtin_amdgcn_s_setprio(0);
    };

    // ---- pipelined main loop: 32 s-tiles, ONE barrier per tile ----
    // tile j: K -> Kb[j&1], V -> Vb[j&3]; S(j) at step j, PV(j) at step j+1.
    loadR(0, ak0, ak1, av0, av1);
    writeL(Kb0, Vb0, ak0, ak1, av0, av1);
    __syncthreads();
    loadR(1, ak0, ak1, av0, av1);

    // step 0: S(0) (no PV yet); stage tile 1
    loadR(2, bk0, bk1, bv0, bv1);
    computeS(Kb0, paA);
    writeL(Kb1, Vb1, ak0, ak1, av0, av1);
    __syncthreads();

    // step 1: PV(0), S(1); stage tile 2
    loadR(3, ak0, ak1, av0, av1);
    computePV(Vb0, paA);
    computeS(Kb1, paB);
    writeL(Kb0, Vb2, bk0, bk1, bv0, bv1);
    __syncthreads();

    // steps 2..29 (7 x 4 steps, all buffer indices static)
    for (int n = 0; n < 7; ++n) {
        const int base = 2 + n * 4;
        loadR(base + 2, bk0, bk1, bv0, bv1);
        computePV(Vb1, paB);              // V(base-1)
        computeS(Kb0, paA);               // S(base)
        writeL(Kb1, Vb3, ak0, ak1, av0, av1);   // tile base+1
        __syncthreads();

        loadR(base + 3, ak0, ak1, av0, av1);
        computePV(Vb2, paA);              // V(base)
        computeS(Kb1, paB);               // S(base+1)
        writeL(Kb0, Vb0, bk0, bk1, bv0, bv1);   // tile base+2
        __syncthreads();

        loadR(base + 4, bk0, bk1, bv0, bv1);
        computePV(Vb3, paB);              // V(base+1)
        computeS(Kb0, paA);               // S(base+2)
        writeL(Kb1, Vb1, ak0, ak1, av0, av1);   // tile base+3
        __syncthreads();

        loadR(base + 5, ak0, ak1, av0, av1);
        computePV(Vb0, paA);              // V(base+2)
        computeS(Kb1, paB);               // S(base+3)
        writeL(Kb0, Vb2, bk0, bk1, bv0, bv1);   // tile base+4
        __syncthreads();
    }

    // step 30: PV(29), S(30); stage tile 31
    computePV(Vb1, paB);
    computeS(Kb0, paA);
    writeL(Kb1, Vb3, ak0, ak1, av0, av1);
    __syncthreads();
    // step 31: PV(30), S(31)
    computePV(Vb2, paA);
    computeS(Kb1, paB);
    // drain: PV(31)
    computePV(Vb3, paB);

    // ---- epilogue: l already in oacc layout; store O/l ----
    #pragma unroll
    for (int mr = 0; mr < 2; ++mr) {
        float inv[4];
        #pragma unroll
        for (int r = 0; r < 4; ++r) inv[r] = 1.0f / lacc[mr][r];
        #pragma unroll
        for (int ds = 0; ds < 4; ++ds)
            #pragma unroll
            for (int r = 0; r < 4; ++r) {
                const float val = oacc[mr][ds][r] * inv[r];
                o[(size_t)(b * TT + t0 + w * 32 + mr * 16 + quad * 4 + r) * EE +
                  h * DD + ds * 16 + l15] = (__bf16)val;
            }
    }
}

// ---------------------------------------------------------------------------
extern "C" void kernel_launch(void* const* d_in, const int* in_sizes, int n_in,
                              void* d_out, int out_size, void* d_ws, size_t ws_size,
                              hipStream_t stream)
{
    const float* x     = (const float*)d_in[0];
    const float* watt  = (const float*)d_in[1];
    const float* wv_w  = (const float*)d_in[2];
    const float* wv_b  = (const float*)d_in[3];
    const float* out_w = (const float*)d_in[4];
    const float* out_b = (const float*)d_in[5];
    float* out = (float*)d_out;

    __bf16* xhi = (__bf16*)d_ws;                         // B*T*E
    __bf16* wvb = xhi + (size_t)BB * TT * EE;            // E*E
    __bf16* owb = wvb + (size_t)EE * EE;                 // E*E
    __bf16* vxT = owb + (size_t)EE * EE;                 // B*H*D*T
    __bf16* obf = vxT + (size_t)BB * HH * DD * TT;       // B*T*E

    const int M = BB * TT;  // 4096

    cast_all<<<3072, 256, 0, stream>>>(x, wv_w, out_w, xhi, wvb, owb);

    // vx = x @ wv_w^T + wv_b, written transposed bf16 as (B,H,D,T)
    gemm_bf16<1><<<(M / 64) * (EE / 128), 512, 0, stream>>>(
        xhi, wvb, wv_b, (void*)vxT, M, EE, EE);

    // fused bilinear attention -> obf (B,T,E) bf16
    attn_mfma<<<dim3(TT / 128, HH, BB), 256, 0, stream>>>(x, xhi, watt, vxT, obf);

    // out = o @ out_w^T + out_b (fp32 out)
    gemm_bf16<0><<<(M / 64) * (EE / 128), 512, 0, stream>>>(
        obf, owb, out_b, (void*)out, M, EE, EE);
}

// Round 2
// 161.791 us; speedup vs baseline: 1.0751x; 1.0605x over previous
//
#include <hip/hip_runtime.h>
#include <hip/hip_bf16.h>
#include <math.h>

constexpr int BB = 2;
constexpr int TT = 2048;
constexpr int EE = 1024;
constexpr int HH = 16;
constexpr int DD = 64;

typedef __bf16 v8bf __attribute__((ext_vector_type(8)));
typedef __bf16 v4bf __attribute__((ext_vector_type(4)));
typedef short  v4s  __attribute__((ext_vector_type(4)));
typedef float  v4f  __attribute__((ext_vector_type(4)));

#define MFMA16(a, b, c) __builtin_amdgcn_mfma_f32_16x16x32_bf16(a, b, c, 0, 0, 0)
#define MFMA16K16(a, b, c) __builtin_amdgcn_mfma_f32_16x16x16bf16_1k(a, b, c, 0, 0, 0)

// async global -> LDS, 16 B per lane; LDS dest = wave-uniform base + lane*16
__device__ __forceinline__ void gll16(const void* g, void* l) {
    __builtin_amdgcn_global_load_lds(
        (const __attribute__((address_space(1))) unsigned int*)g,
        (__attribute__((address_space(3))) unsigned int*)(unsigned)(uintptr_t)l,
        16, 0, 0);
}

// ---------------------------------------------------------------------------
// cast_all: x -> x_hi (bf16), wv_w -> bf16, out_w -> bf16.  8 elems/thread.
// ---------------------------------------------------------------------------
__global__ __launch_bounds__(256) void cast_all(
    const float* __restrict__ x, const float* __restrict__ wv,
    const float* __restrict__ ow,
    __bf16* __restrict__ xhi, __bf16* __restrict__ wvb, __bf16* __restrict__ owb)
{
    const int bid = blockIdx.x;
    const float* src;
    __bf16* dst;
    int base;
    if (bid < 2048)      { src = x;  dst = xhi; base = bid; }
    else if (bid < 2560) { src = wv; dst = wvb; base = bid - 2048; }
    else                 { src = ow; dst = owb; base = bid - 2560; }
    const size_t i = (size_t)base * 256 + threadIdx.x;
    float4 f0 = ((const float4*)src)[i * 2];
    float4 f1 = ((const float4*)src)[i * 2 + 1];
    float f[8] = {f0.x, f0.y, f0.z, f0.w, f1.x, f1.y, f1.z, f1.w};
    v8bf h;
    #pragma unroll
    for (int j = 0; j < 8; ++j) h[j] = (__bf16)f[j];
    *(v8bf*)(dst + i * 8) = h;
}

// ---------------------------------------------------------------------------
// bf16 MFMA GEMM, counted-vmcnt deep pipeline (T3+T4):
// 128x128 tile, BK=64, 512 thr, 4-deep LDS ring (128 KB), grid 256 = 1 blk/CU.
// Per iter: stage tile i+2 (4 x gll16/thread), s_waitcnt vmcnt(8) (tiles
// i+1,i+2 stay IN FLIGHT across the barrier -- never drain to 0), raw
// s_barrier, 12 x ds_read_b128 + 16 MFMA.  Ring distance proof: stager in
// iter j writes buf[(j+2)&3]; barrier order confines readers to iter j-1
// reading buf[(j-1)&3] -> distance 3 mod 4, disjoint.
// XOR chunk swizzle (c ^= row&7) pre-applied on the global source so the
// linear gll16 dest yields conflict-free ds_read_b128 (8 lanes/bank-group).
// XCD-banded mapping: each XCD gets 8 m-tiles x 4 n-tiles (2MB+1MB in L2).
// MODE 0: C fp32 row-major; MODE 1: C bf16 as vxT (B,H,D,T)
// ---------------------------------------------------------------------------
template <int MODE>
__global__ __launch_bounds__(512) void gemm_bf16(
    const __bf16* __restrict__ A, const __bf16* __restrict__ Bw,
    const float* __restrict__ bias, void* __restrict__ Cout,
    int M, int N, int K)
{
    __shared__ __bf16 Ah[4][128][64];   // 64 KB
    __shared__ __bf16 Bh[4][128][64];   // 64 KB

    const int tid = threadIdx.x;
    const int w = tid >> 6, lane = tid & 63, quad = lane >> 4, l15 = lane & 15;
    const int bid = blockIdx.x;
    const int xcd = bid & 7, slot = bid >> 3;
    const int bx = (xcd & 1) * 4 + (slot & 3);     // n-tile 0..7
    const int by = (xcd >> 1) * 8 + (slot >> 2);   // m-tile 0..31
    const int m0 = by * 128, n0 = bx * 128;
    const int wm = (w >> 2) * 64, wn = (w & 3) * 32;

    v4f acc[4][2] = {};
    float bn[2];
    #pragma unroll
    for (int ns = 0; ns < 2; ++ns) bn[ns] = bias[n0 + wn + ns * 16 + l15];

    // staging: thread covers one 16B chunk; 2 rounds of 64 rows per matrix.
    // LDS row = 8w + (lane>>3) (+64 round 1); chunk = lane&7.
    // source chunk pre-swizzled: ch = (lane&7) ^ (row&7), row&7 == lane>>3.
    const int sr8 = lane >> 3;
    const int ch  = (lane & 7) ^ sr8;
    const __bf16* ag = A + (size_t)(m0 + 8 * w + sr8) * K + ch * 8;
    const __bf16* bg = Bw + (size_t)(n0 + 8 * w + sr8) * K + ch * 8;
    const size_t rk = (size_t)64 * K;

    auto stage = [&](int t, int bi) {
        const size_t ko = (size_t)t * 64;
        gll16(ag + ko,      &Ah[bi][8 * w][0]);
        gll16(ag + rk + ko, &Ah[bi][64 + 8 * w][0]);
        gll16(bg + ko,      &Bh[bi][8 * w][0]);
        gll16(bg + rk + ko, &Bh[bi][64 + 8 * w][0]);
    };
    auto compute = [&](int bi) {
        #pragma unroll
        for (int kk = 0; kk < 2; ++kk) {
            v8bf af[4], bf2[2];
            #pragma unroll
            for (int ms = 0; ms < 4; ++ms) {
                const int r = wm + ms * 16 + l15;
                af[ms] = *(const v8bf*)&Ah[bi][r][(((kk << 2) + quad) ^ (r & 7)) * 8];
            }
            #pragma unroll
            for (int ns = 0; ns < 2; ++ns) {
                const int r = wn + ns * 16 + l15;
                bf2[ns] = *(const v8bf*)&Bh[bi][r][(((kk << 2) + quad) ^ (r & 7)) * 8];
            }
            #pragma unroll
            for (int ms = 0; ms < 4; ++ms)
                #pragma unroll
                for (int ns = 0; ns < 2; ++ns)
                    acc[ms][ns] = MFMA16(af[ms], bf2[ns], acc[ms][ns]);
        }
    };

    const int NIT = K >> 6;             // 16 for K=1024
    stage(0, 0);
    stage(1, 1);
    for (int it = 0; it + 2 < NIT; ++it) {
        stage(it + 2, (it + 2) & 3);
        asm volatile("s_waitcnt vmcnt(8)" ::: "memory");
        __builtin_amdgcn_s_barrier();
        asm volatile("" ::: "memory");
        compute(it & 3);
    }
    asm volatile("s_waitcnt vmcnt(4)" ::: "memory");
    __builtin_amdgcn_s_barrier();
    asm volatile("" ::: "memory");
    compute((NIT - 2) & 3);
    asm volatile("s_waitcnt vmcnt(0)" ::: "memory");
    __builtin_amdgcn_s_barrier();
    asm volatile("" ::: "memory");
    compute((NIT - 1) & 3);

    #pragma unroll
    for (int ms = 0; ms < 4; ++ms) {
        const int mbase = m0 + wm + ms * 16 + quad * 4;
        #pragma unroll
        for (int ns = 0; ns < 2; ++ns) {
            const int n = n0 + wn + ns * 16 + l15;
            if (MODE == 0) {
                float* C = (float*)Cout;
                #pragma unroll
                for (int r = 0; r < 4; ++r)
                    C[(size_t)(mbase + r) * N + n] = acc[ms][ns][r] + bn[ns];
            } else {
                const int bq = mbase >> 11, t = mbase & 2047;
                const int hh = n >> 6, dd = n & 63;
                v4bf pk;
                #pragma unroll
                for (int r = 0; r < 4; ++r) pk[r] = (__bf16)(acc[ms][ns][r] + bn[ns]);
                *(v4bf*)((__bf16*)Cout + (((size_t)bq * HH + hh) * DD + dd) * TT + t) = pk;
            }
        }
    }
}

// ---------------------------------------------------------------------------
// MFMA flash attention, software-pipelined: PV of tile j-1 issues before
// S of tile j (pa fragments held in registers across one barrier), so each
// wave always has a dependency-free MFMA cluster to hide the exp2/softmax
// VALU chain.  K double-buffered, V quad-buffered (V lifetime = 2 steps);
// all buffers overlay the dead phase-0 X/W regions -> LDS stays 55,296 B,
// 2 blocks/CU, ONE barrier per s-tile.  s_setprio around MFMA clusters.
// ---------------------------------------------------------------------------
__global__ __launch_bounds__(256, 2) void attn_mfma(
    const float* __restrict__ x,      // (B,T,E) fp32 (phase-0 Q input)
    const __bf16* __restrict__ xh,    // (B,T,E) bf16 (K)
    const float* __restrict__ watt,   // (H,D,D) fp32
    const __bf16* __restrict__ vxT,   // (B,H,D,T) bf16
    __bf16* __restrict__ o)           // (B,T,E) bf16
{
    constexpr int LDP = 72;
    __shared__ __bf16 SM[384][LDP];   // 55,296 B, overlaid:
    // phase 0:  XH rows 0..127, XL rows 128..255, Wh 256..319, Wl 320..383
    // main:     Kb0 0..63, Kb1 64..127, Vb0 128..191, Vb1 192..255,
    //           Vb2 256..319, Vb3 320..383
    __bf16 (*XH)[LDP]  = SM;
    __bf16 (*XL)[LDP]  = SM + 128;
    __bf16 (*Wh)[LDP]  = SM + 256;
    __bf16 (*Wl)[LDP]  = SM + 320;
    __bf16 (*Kb0)[LDP] = SM;
    __bf16 (*Kb1)[LDP] = SM + 64;
    __bf16 (*Vb0)[LDP] = SM + 128;
    __bf16 (*Vb1)[LDP] = SM + 192;
    __bf16 (*Vb2)[LDP] = SM + 256;
    __bf16 (*Vb3)[LDP] = SM + 320;

    const int tid = threadIdx.x;
    const int w = tid >> 6, lane = tid & 63, quad = lane >> 4, l15 = lane & 15;
    const int qt = blockIdx.x, h = blockIdx.y, b = blockIdx.z;
    const int t0 = qt * 128;

    // scale: 1/sqrt(D) * log2(e)  (scores computed in log2 domain -> exp2)
    const float WSC = 0.125f * 1.4426950408889634f;

    // ---- phase 0: stage X q-tile (fp32 -> hi/lo) and W_h^T (scaled, hi/lo)
    {
        const int row = tid >> 1, half = (tid & 1) * 32;
        const float* xp = x + ((size_t)(b * TT + t0 + row)) * EE + h * DD + half;
        #pragma unroll
        for (int c = 0; c < 4; ++c) {
            float4 f0 = ((const float4*)xp)[c * 2];
            float4 f1 = ((const float4*)xp)[c * 2 + 1];
            float f[8] = {f0.x, f0.y, f0.z, f0.w, f1.x, f1.y, f1.z, f1.w};
            v8bf hi, lo;
            #pragma unroll
            for (int j = 0; j < 8; ++j) {
                __bf16 hv = (__bf16)f[j];
                hi[j] = hv;
                lo[j] = (__bf16)(f[j] - (float)hv);
            }
            *(v8bf*)&XH[row][half + c * 8] = hi;
            *(v8bf*)&XL[row][half + c * 8] = lo;
        }
        const int r = tid >> 2, c0 = (tid & 3) * 16;
        const float* wp = watt + ((size_t)h * DD + r) * DD + c0;
        #pragma unroll
        for (int i = 0; i < 16; ++i) {
            const float f = wp[i] * WSC;
            __bf16 hv = (__bf16)f;
            Wh[c0 + i][r] = hv;                      // Wt_hi[e_out][d]
            Wl[c0 + i][r] = (__bf16)(f - (float)hv); // Wt_lo
        }
    }
    __syncthreads();

    // ---- Q = X_hi Wt_hi + X_hi Wt_lo + X_lo Wt_hi  (wave rows 32w..32w+32)
    v4f qacc[2][4] = {};
    #pragma unroll
    for (int kk = 0; kk < 2; ++kk) {
        v8bf xhf[2], xlf[2];
        #pragma unroll
        for (int mr = 0; mr < 2; ++mr) {
            xhf[mr] = *(const v8bf*)&XH[w * 32 + mr * 16 + l15][kk * 32 + quad * 8];
            xlf[mr] = *(const v8bf*)&XL[w * 32 + mr * 16 + l15][kk * 32 + quad * 8];
        }
        #pragma unroll
        for (int ns = 0; ns < 4; ++ns) {
            v8bf wh = *(const v8bf*)&Wh[ns * 16 + l15][kk * 32 + quad * 8];
            v8bf wl = *(const v8bf*)&Wl[ns * 16 + l15][kk * 32 + quad * 8];
            #pragma unroll
            for (int mr = 0; mr < 2; ++mr) {
                qacc[mr][ns] = MFMA16(xlf[mr], wh, qacc[mr][ns]);
                qacc[mr][ns] = MFMA16(xhf[mr], wl, qacc[mr][ns]);
                qacc[mr][ns] = MFMA16(xhf[mr], wh, qacc[mr][ns]);
            }
        }
    }
    __syncthreads();  // all waves done reading X/W regions

    // write Q hi/lo (C-layout scatter, wave-local rows), reload as frags
    #pragma unroll
    for (int mr = 0; mr < 2; ++mr)
        #pragma unroll
        for (int ns = 0; ns < 4; ++ns)
            #pragma unroll
            for (int r = 0; r < 4; ++r) {
                const float f = qacc[mr][ns][r];
                __bf16 hv = (__bf16)f;
                XH[w * 32 + mr * 16 + quad * 4 + r][ns * 16 + l15] = hv;
                XL[w * 32 + mr * 16 + quad * 4 + r][ns * 16 + l15] = (__bf16)(f - (float)hv);
            }
    v8bf qh[2][2], ql[2][2];
    #pragma unroll
    for (int mr = 0; mr < 2; ++mr)
        #pragma unroll
        for (int kk = 0; kk < 2; ++kk) {
            qh[mr][kk] = *(const v8bf*)&XH[w * 32 + mr * 16 + l15][kk * 32 + quad * 8];
            ql[mr][kk] = *(const v8bf*)&XL[w * 32 + mr * 16 + l15][kk * 32 + quad * 8];
        }
    __syncthreads();  // Q reloads done before staging overwrites SM

    v4f oacc[2][4] = {};
    v4f lacc[2] = {};
    v4s ones;
    #pragma unroll
    for (int j = 0; j < 4; ++j) ones[j] = (short)0x3F80;  // bf16 1.0

    const __bf16* kb = xh + (size_t)b * TT * EE + h * DD;
    const __bf16* vb = vxT + ((size_t)(b * HH + h)) * DD * TT;
    const int kr = tid >> 2, kc = (tid & 3) * 16;

    uint4 ak0, ak1, av0, av1, bk0, bk1, bv0, bv1;
    v4s paA[2][4], paB[2][4];

    auto loadR = [&](int idx, uint4& k0, uint4& k1, uint4& v0, uint4& v1) {
        const int s0 = idx * 64;
        k0 = *(const uint4*)(kb + (size_t)(s0 + kr) * EE + kc);
        k1 = *(const uint4*)(kb + (size_t)(s0 + kr) * EE + kc + 8);
        v0 = *(const uint4*)(vb + (size_t)kr * TT + s0 + kc);
        v1 = *(const uint4*)(vb + (size_t)kr * TT + s0 + kc + 8);
    };
    auto writeL = [&](__bf16 (*kbuf)[LDP], __bf16 (*vbuf)[LDP],
                      const uint4& k0, const uint4& k1,
                      const uint4& v0, const uint4& v1) {
        *(uint4*)&kbuf[kr][kc] = k0;
        *(uint4*)&kbuf[kr][kc + 8] = k1;
        *(uint4*)&vbuf[kr][kc] = v0;
        *(uint4*)&vbuf[kr][kc + 8] = v1;
    };
    // S^T = K (Q_hi + Q_lo)^T -> exp2 -> pa fragments (registers)
    auto computeS = [&](__bf16 (*kbuf)[LDP], v4s (*pa)[4]) {
        v4f sacc[2][4] = {};
        __builtin_amdgcn_s_setprio(1);
        #pragma unroll
        for (int kk = 0; kk < 2; ++kk)
            #pragma unroll
            for (int ss = 0; ss < 4; ++ss) {
                v8bf kf = *(const v8bf*)&kbuf[ss * 16 + l15][kk * 32 + quad * 8];
                #pragma unroll
                for (int mr = 0; mr < 2; ++mr) {
                    sacc[mr][ss] = MFMA16(kf, ql[mr][kk], sacc[mr][ss]);
                    sacc[mr][ss] = MFMA16(kf, qh[mr][kk], sacc[mr][ss]);
                }
            }
        __builtin_amdgcn_s_setprio(0);
        #pragma unroll
        for (int mr = 0; mr < 2; ++mr)
            #pragma unroll
            for (int ss = 0; ss < 4; ++ss) {
                v4bf pb;
                #pragma unroll
                for (int r = 0; r < 4; ++r)
                    pb[r] = (__bf16)__builtin_amdgcn_exp2f(sacc[mr][ss][r]);
                union { v4bf b; v4s s; } u;
                u.b = pb;
                pa[mr][ss] = u.s;
            }
    };
    // l += P 1 ; O += P V   (pa of the PREVIOUS tile -> zero-dep MFMAs)
    auto computePV = [&](__bf16 (*vbuf)[LDP], v4s (*pa)[4]) {
        __builtin_amdgcn_s_setprio(1);
        #pragma unroll
        for (int mr = 0; mr < 2; ++mr)
            #pragma unroll
            for (int ss = 0; ss < 4; ++ss)
                lacc[mr] = MFMA16K16(pa[mr][ss], ones, lacc[mr]);
        #pragma unroll
        for (int ss = 0; ss < 4; ++ss)
            #pragma unroll
            for (int ds = 0; ds < 4; ++ds) {
                v4s vf = *(const v4s*)&vbuf[ds * 16 + l15][ss * 16 + quad * 4];
                #pragma unroll
                for (int mr = 0; mr < 2; ++mr)
                    oacc[mr][ds] = MFMA16K16(pa[mr][ss], vf, oacc[mr][ds]);
            }
        __builtin_amdgcn_s_setprio(0);
    };

    // ---- pipelined main loop: 32 s-tiles, ONE barrier per tile ----
    // tile j: K -> Kb[j&1], V -> Vb[j&3]; S(j) at step j, PV(j) at step j+1.
    loadR(0, ak0, ak1, av0, av1);
    writeL(Kb0, Vb0, ak0, ak1, av0, av1);
    __syncthreads();
    loadR(1, ak0, ak1, av0, av1);

    // step 0: S(0) (no PV yet); stage tile 1
    loadR(2, bk0, bk1, bv0, bv1);
    computeS(Kb0, paA);
    writeL(Kb1, Vb1, ak0, ak1, av0, av1);
    __syncthreads();

    // step 1: PV(0), S(1); stage tile 2
    loadR(3, ak0, ak1, av0, av1);
    computePV(Vb0, paA);
    computeS(Kb1, paB);
    writeL(Kb0, Vb2, bk0, bk1, bv0, bv1);
    __syncthreads();

    // steps 2..29 (7 x 4 steps, all buffer indices static)
    for (int n = 0; n < 7; ++n) {
        const int base = 2 + n * 4;
        loadR(base + 2, bk0, bk1, bv0, bv1);
        computePV(Vb1, paB);              // V(base-1)
        computeS(Kb0, paA);               // S(base)
        writeL(Kb1, Vb3, ak0, ak1, av0, av1);   // tile base+1
        __syncthreads();

        loadR(base + 3, ak0, ak1, av0, av1);
        computePV(Vb2, paA);              // V(base)
        computeS(Kb1, paB);               // S(base+1)
        writeL(Kb0, Vb0, bk0, bk1, bv0, bv1);   // tile base+2
        __syncthreads();

        loadR(base + 4, bk0, bk1, bv0, bv1);
        computePV(Vb3, paB);              // V(base+1)
        computeS(Kb0, paA);               // S(base+2)
        writeL(Kb1, Vb1, ak0, ak1, av0, av1);   // tile base+3
        __syncthreads();

        loadR(base + 5, ak0, ak1, av0, av1);
        computePV(Vb0, paA);              // V(base+2)
        computeS(Kb1, paB);               // S(base+3)
        writeL(Kb0, Vb2, bk0, bk1, bv0, bv1);   // tile base+4
        __syncthreads();
    }

    // step 30: PV(29), S(30); stage tile 31
    computePV(Vb1, paB);
    computeS(Kb0, paA);
    writeL(Kb1, Vb3, ak0, ak1, av0, av1);
    __syncthreads();
    // step 31: PV(30), S(31)
    computePV(Vb2, paA);
    computeS(Kb1, paB);
    // drain: PV(31)
    computePV(Vb3, paB);

    // ---- epilogue: l already in oacc layout; store O/l ----
    #pragma unroll
    for (int mr = 0; mr < 2; ++mr) {
        float inv[4];
        #pragma unroll
        for (int r = 0; r < 4; ++r) inv[r] = 1.0f / lacc[mr][r];
        #pragma unroll
        for (int ds = 0; ds < 4; ++ds)
            #pragma unroll
            for (int r = 0; r < 4; ++r) {
                const float val = oacc[mr][ds][r] * inv[r];
                o[(size_t)(b * TT + t0 + w * 32 + mr * 16 + quad * 4 + r) * EE +
                  h * DD + ds * 16 + l15] = (__bf16)val;
            }
    }
}

// ---------------------------------------------------------------------------
extern "C" void kernel_launch(void* const* d_in, const int* in_sizes, int n_in,
                              void* d_out, int out_size, void* d_ws, size_t ws_size,
                              hipStream_t stream)
{
    const float* x     = (const float*)d_in[0];
    const float* watt  = (const float*)d_in[1];
    const float* wv_w  = (const float*)d_in[2];
    const float* wv_b  = (const float*)d_in[3];
    const float* out_w = (const float*)d_in[4];
    const float* out_b = (const float*)d_in[5];
    float* out = (float*)d_out;

    __bf16* xhi = (__bf16*)d_ws;                         // B*T*E
    __bf16* wvb = xhi + (size_t)BB * TT * EE;            // E*E
    __bf16* owb = wvb + (size_t)EE * EE;                 // E*E
    __bf16* vxT = owb + (size_t)EE * EE;                 // B*H*D*T
    __bf16* obf = vxT + (size_t)BB * HH * DD * TT;       // B*T*E

    const int M = BB * TT;  // 4096

    cast_all<<<3072, 256, 0, stream>>>(x, wv_w, out_w, xhi, wvb, owb);

    // vx = x @ wv_w^T + wv_b, written transposed bf16 as (B,H,D,T)
    gemm_bf16<1><<<(M / 128) * (EE / 128), 512, 0, stream>>>(
        xhi, wvb, wv_b, (void*)vxT, M, EE, EE);

    // fused bilinear attention -> obf (B,T,E) bf16
    attn_mfma<<<dim3(TT / 128, HH, BB), 256, 0, stream>>>(x, xhi, watt, vxT, obf);

    // out = o @ out_w^T + out_b (fp32 out)
    gemm_bf16<0><<<(M / 128) * (EE / 128), 512, 0, stream>>>(
        obf, owb, out_b, (void*)out, M, EE, EE);
}